// Round 1
// 805.268 us; speedup vs baseline: 1.4247x; 1.4247x over previous
//
#include <hip/hip_runtime.h>
#include <cstdint>
#include <cstddef>

#define B_ 8
#define C_ 256
#define CQ 32
#define N_ 4096

typedef __attribute__((ext_vector_type(8))) short bf16x8;
typedef __attribute__((ext_vector_type(4))) float f32x4;

__device__ __forceinline__ short f2bf(float f) {
    union { float f; uint32_t u; } v; v.f = f;
    uint32_t r = (v.u + 0x7FFFu + ((v.u >> 16) & 1u)) >> 16;   // RNE
    return (short)r;
}

// ---------------- K0: weights fp32 -> bf16 ----------------
__global__ __launch_bounds__(256) void wconv(const float* wq, const float* wk, const float* wv,
                                             short* wqb, short* wkb, short* wvb) {
    int i = blockIdx.x * 256 + threadIdx.x;        // grid 256 blocks -> 65536 threads
    if (i < 8192) { wqb[i] = f2bf(wq[i]); wkb[i] = f2bf(wk[i]); }
    if (i < 65536) wvb[i] = f2bf(wv[i]);
}

// ---------------- K1: x[b][c][n] -> xb_t[b][n][c] (bf16) ----------------
__global__ __launch_bounds__(256) void xpose(const float* x, short* xbt) {
    int blk = blockIdx.x;            // 8 * 128 * 8 = 8192 blocks
    int b = blk >> 10;
    int rem = blk & 1023;
    int nt = rem >> 3, ct = rem & 7;
    int n0 = nt * 32, c0 = ct * 32;
    __shared__ short tile[32][33];
    int tx = threadIdx.x & 31, ty = threadIdx.x >> 5;    // ty 0..7
    const float* xb = x + (size_t)b * C_ * N_;
#pragma unroll
    for (int i = 0; i < 4; i++) {
        int c = c0 + ty + i * 8;
        tile[ty + i * 8][tx] = f2bf(xb[(size_t)c * N_ + n0 + tx]);
    }
    __syncthreads();
    short* dst = xbt + (size_t)b * N_ * C_;
#pragma unroll
    for (int i = 0; i < 4; i++) {
        int n = n0 + ty + i * 8;
        dst[(size_t)n * C_ + c0 + tx] = tile[tx][ty + i * 8];
    }
}

// ---------------- K2: q/k projection -> q_t/k_t [b][n][32] bf16 ----------------
__global__ __launch_bounds__(256) void qkproj(const short* xbt, const short* wqb, const short* wkb,
                                              const float* bq, const float* bk,
                                              short* qt, short* kt) {
    int w = threadIdx.x >> 6, lane = threadIdx.x & 63;
    int gw = blockIdx.x * 4 + w;          // 2048 waves = 8 b * 256 n-tiles
    int b = gw >> 8, nt = gw & 255;
    int n0 = nt * 16;
    int col = lane & 15, quad = lane >> 4;
    const bf16x8* arow = (const bf16x8*)(xbt + ((size_t)(b * N_ + n0 + col)) * C_ + quad * 8);
    const bf16x8* q0p = (const bf16x8*)(wqb + (size_t)col * C_ + quad * 8);
    const bf16x8* q1p = (const bf16x8*)(wqb + (size_t)(16 + col) * C_ + quad * 8);
    const bf16x8* k0p = (const bf16x8*)(wkb + (size_t)col * C_ + quad * 8);
    const bf16x8* k1p = (const bf16x8*)(wkb + (size_t)(16 + col) * C_ + quad * 8);
    f32x4 aq0 = {0,0,0,0}, aq1 = {0,0,0,0}, ak0 = {0,0,0,0}, ak1 = {0,0,0,0};
#pragma unroll
    for (int ks = 0; ks < 8; ks++) {
        bf16x8 a = arow[ks * 4];          // +32 shorts per k-step
        aq0 = __builtin_amdgcn_mfma_f32_16x16x32_bf16(a, q0p[ks * 4], aq0, 0, 0, 0);
        aq1 = __builtin_amdgcn_mfma_f32_16x16x32_bf16(a, q1p[ks * 4], aq1, 0, 0, 0);
        ak0 = __builtin_amdgcn_mfma_f32_16x16x32_bf16(a, k0p[ks * 4], ak0, 0, 0, 0);
        ak1 = __builtin_amdgcn_mfma_f32_16x16x32_bf16(a, k1p[ks * 4], ak1, 0, 0, 0);
    }
    float bq0 = bq[col], bq1 = bq[16 + col], bk0 = bk[col], bk1 = bk[16 + col];
#pragma unroll
    for (int r = 0; r < 4; r++) {
        int n = n0 + quad * 4 + r;        // D row = quad*4+reg
        size_t base = ((size_t)b * N_ + n) * CQ;
        qt[base + col]      = f2bf(aq0[r] + bq0);
        qt[base + 16 + col] = f2bf(aq1[r] + bq1);
        kt[base + col]      = f2bf(ak0[r] + bk0);
        kt[base + 16 + col] = f2bf(ak1[r] + bk1);
    }
}

// ---------------- K3: v projection -> v[b][c][n] bf16 ----------------
__global__ __launch_bounds__(256) void vproj(const short* xbt, const short* wvb,
                                             const float* bv, short* vb) {
    int w = threadIdx.x >> 6, lane = threadIdx.x & 63;
    int gw = blockIdx.x * 4 + w;          // 8192 waves = 8 * 16 * 64
    int b = gw >> 10;
    int rem = gw & 1023;
    int ct = rem >> 6, nt = rem & 63;
    int c0 = ct * 16, n0 = nt * 64;
    int col = lane & 15, quad = lane >> 4;
    const bf16x8* arow = (const bf16x8*)(wvb + (size_t)(c0 + col) * C_ + quad * 8);
    const bf16x8* brow[4];
#pragma unroll
    for (int j = 0; j < 4; j++)
        brow[j] = (const bf16x8*)(xbt + ((size_t)b * N_ + n0 + j * 16 + col) * C_ + quad * 8);
    f32x4 acc[4];
#pragma unroll
    for (int j = 0; j < 4; j++) acc[j] = (f32x4){0,0,0,0};
#pragma unroll
    for (int ks = 0; ks < 8; ks++) {
        bf16x8 a = arow[ks * 4];
#pragma unroll
        for (int j = 0; j < 4; j++)
            acc[j] = __builtin_amdgcn_mfma_f32_16x16x32_bf16(a, brow[j][ks * 4], acc[j], 0, 0, 0);
    }
#pragma unroll
    for (int r = 0; r < 4; r++) {
        int c = c0 + quad * 4 + r;
        float bias = bv[c];
        size_t base = ((size_t)b * C_ + c) * N_ + n0;
#pragma unroll
        for (int j = 0; j < 4; j++)
            vb[base + j * 16 + col] = f2bf(acc[j][r] + bias);
    }
}

// ---------------- K4: fused energy + softmax + PV + blend ----------------
// 512 blocks (8 b x 64 n-tiles), 4 waves.
// Pass 1: wave w owns n-rows [nw, nw+16): recompute E = q.k via MFMA, online
//         row max/sumexp in registers, butterfly allreduce over 16 col-lanes.
// Pass 2: recompute E, p = exp(e-m)*inv_s, nontemporal-store p to attn (only
//         HBM attn traffic), stage bf16 p in dbuf LDS (1 barrier per 64-m
//         step), PV: 32 MFMAs/step with wave's 64-c slice against all 64 n.
__global__ __launch_bounds__(256) void fused_attn(const short* qt, const short* kt,
                                                  const short* vb, const float* x,
                                                  const float* gamma, float* out, float* attn) {
    int blk = blockIdx.x;                 // 512 = 8 b * 64 nt
    int b = blk >> 6, nt = blk & 63;
    int n0 = nt * 64;
    int t = threadIdx.x;
    int w = t >> 6, lane = t & 63;
    int col = lane & 15, quad = lane >> 4;
    int nw = n0 + w * 16;                 // wave's energy n-sub base

    bf16x8 qf = *(const bf16x8*)(qt + ((size_t)(b * N_ + nw + col)) * CQ + quad * 8);
    const short* kbase = kt + (size_t)b * N_ * CQ + quad * 8;

    // ---- pass 1: per-row max & sum of exp (rows nw + quad*4 + r) ----
    float mr[4], sr[4];
#pragma unroll
    for (int r = 0; r < 4; r++) { mr[r] = -1e30f; sr[r] = 0.f; }
    for (int m0 = 0; m0 < N_; m0 += 64) {
        f32x4 ev[4];
#pragma unroll
        for (int j = 0; j < 4; j++) {
            bf16x8 kf = *(const bf16x8*)(kbase + (size_t)(m0 + j * 16 + col) * CQ);
            ev[j] = __builtin_amdgcn_mfma_f32_16x16x32_bf16(qf, kf, (f32x4){0,0,0,0}, 0, 0, 0);
        }
#pragma unroll
        for (int r = 0; r < 4; r++) {
            float tm = fmaxf(fmaxf(ev[0][r], ev[1][r]), fmaxf(ev[2][r], ev[3][r]));
            float nm = fmaxf(mr[r], tm);
            sr[r] = sr[r] * __expf(mr[r] - nm)
                  + __expf(ev[0][r] - nm) + __expf(ev[1][r] - nm)
                  + __expf(ev[2][r] - nm) + __expf(ev[3][r] - nm);
            mr[r] = nm;
        }
    }
    // butterfly allreduce across the 16 col-lanes (m-slices of each row)
#pragma unroll
    for (int off = 1; off < 16; off <<= 1) {
#pragma unroll
        for (int r = 0; r < 4; r++) {
            float mo = __shfl_xor(mr[r], off, 64);
            float so = __shfl_xor(sr[r], off, 64);
            float nm = fmaxf(mr[r], mo);
            sr[r] = sr[r] * __expf(mr[r] - nm) + so * __expf(mo - nm);
            mr[r] = nm;
        }
    }
    float inv[4];
#pragma unroll
    for (int r = 0; r < 4; r++) inv[r] = 1.0f / sr[r];

    // ---- pass 2: recompute E -> p -> attn store + LDS stage -> PV ----
    __shared__ short pl[2][64][72];       // dbuf, stride 72 shorts (144B, b128-aligned)
    const bf16x8* vrow[4];
#pragma unroll
    for (int i = 0; i < 4; i++)
        vrow[i] = (const bf16x8*)(vb + ((size_t)b * C_ + w * 64 + i * 16 + col) * N_ + quad * 8);
    float* arow[4];
#pragma unroll
    for (int r = 0; r < 4; r++)
        arow[r] = attn + ((size_t)b * N_ + nw + quad * 4 + r) * N_;
    f32x4 acc[4][4];
#pragma unroll
    for (int i = 0; i < 4; i++)
#pragma unroll
        for (int j = 0; j < 4; j++) acc[i][j] = (f32x4){0,0,0,0};

    int par = 0;
    for (int m0 = 0; m0 < N_; m0 += 64) {
        f32x4 ev[4];
#pragma unroll
        for (int j = 0; j < 4; j++) {
            bf16x8 kf = *(const bf16x8*)(kbase + (size_t)(m0 + j * 16 + col) * CQ);
            ev[j] = __builtin_amdgcn_mfma_f32_16x16x32_bf16(qf, kf, (f32x4){0,0,0,0}, 0, 0, 0);
        }
        float pv[4][4];
#pragma unroll
        for (int j = 0; j < 4; j++) {
#pragma unroll
            for (int r = 0; r < 4; r++) {
                float p = __expf(ev[j][r] - mr[r]) * inv[r];
                pv[j][r] = p;
                pl[par][w * 16 + quad * 4 + r][j * 16 + col] = f2bf(p);
            }
        }
        __syncthreads();
        // attn output write AFTER the barrier: store drain overlaps the MFMAs
#pragma unroll
        for (int j = 0; j < 4; j++)
#pragma unroll
            for (int r = 0; r < 4; r++)
                __builtin_nontemporal_store(pv[j][r], arow[r] + m0 + j * 16 + col);
        bf16x8 bfr[2][4];
#pragma unroll
        for (int kk = 0; kk < 2; kk++)
#pragma unroll
            for (int j = 0; j < 4; j++)
                bfr[kk][j] = *(const bf16x8*)&pl[par][j * 16 + col][kk * 32 + quad * 8];
        int ku = m0 >> 3;                 // short8 units along m
#pragma unroll
        for (int kk = 0; kk < 2; kk++) {
#pragma unroll
            for (int i = 0; i < 4; i++) {
                bf16x8 a = vrow[i][ku + kk * 4];
#pragma unroll
                for (int j = 0; j < 4; j++)
                    acc[i][j] = __builtin_amdgcn_mfma_f32_16x16x32_bf16(a, bfr[kk][j], acc[i][j], 0, 0, 0);
            }
        }
        par ^= 1;
    }

    // ---- epilogue: out = 0.5*gamma*o + x ----
    float g = 0.5f * gamma[0];
#pragma unroll
    for (int i = 0; i < 4; i++) {
#pragma unroll
        for (int r = 0; r < 4; r++) {
            int c = w * 64 + i * 16 + quad * 4 + r;
            size_t base = ((size_t)b * C_ + c) * N_ + n0;
#pragma unroll
            for (int j = 0; j < 4; j++) {
                int n = j * 16 + col;
                float o = g * acc[i][j][r] + x[base + n];
                __builtin_nontemporal_store(o, out + base + n);
            }
        }
    }
}

extern "C" void kernel_launch(void* const* d_in, const int* in_sizes, int n_in,
                              void* d_out, int out_size, void* d_ws, size_t ws_size,
                              hipStream_t stream) {
    const float* x     = (const float*)d_in[0];
    const float* Wq    = (const float*)d_in[1];
    const float* bq    = (const float*)d_in[2];
    const float* Wk    = (const float*)d_in[3];
    const float* bk    = (const float*)d_in[4];
    const float* Wv    = (const float*)d_in[5];
    const float* bv    = (const float*)d_in[6];
    const float* gamma = (const float*)d_in[7];
    float* out  = (float*)d_out;
    float* attn = out + (size_t)B_ * C_ * N_;     // attention follows out, flat

    char* ws = (char*)d_ws;                       // ~36 MB used, fully rewritten each call
    short* xbt = (short*)(ws);                    // [B][N][C]  16 MB
    short* qt  = (short*)(ws + 16777216);         // [B][N][32]  2 MB
    short* kt  = (short*)(ws + 18874368);         // [B][N][32]  2 MB
    short* vb  = (short*)(ws + 20971520);         // [B][C][N]  16 MB
    short* wqb = (short*)(ws + 37748736);
    short* wkb = (short*)(ws + 37765120);
    short* wvb = (short*)(ws + 37781504);

    hipLaunchKernelGGL(wconv,     dim3(256),  dim3(256), 0, stream, Wq, Wk, Wv, wqb, wkb, wvb);
    hipLaunchKernelGGL(xpose,     dim3(8192), dim3(256), 0, stream, x, xbt);
    hipLaunchKernelGGL(qkproj,    dim3(512),  dim3(256), 0, stream, xbt, wqb, wkb, bq, bk, qt, kt);
    hipLaunchKernelGGL(vproj,     dim3(2048), dim3(256), 0, stream, xbt, wvb, bv, vb);
    hipLaunchKernelGGL(fused_attn,dim3(512),  dim3(256), 0, stream, qt, kt, vb, x, gamma, out, attn);
}